// Round 21
// baseline (639.528 us; speedup 1.0000x reference)
//
#include <hip/hip_runtime.h>
#include <math.h>

typedef short short8v __attribute__((ext_vector_type(8)));
typedef float f32x4 __attribute__((ext_vector_type(4)));
typedef unsigned short ushort4v __attribute__((ext_vector_type(4)));

#define T_TOK 8192
#define DDIM 1024
#define HDIM 4096
#define NE 8
#define CCAP 2150
#define CPAD 2304   // 9 * 256

__device__ __forceinline__ unsigned short f2bf(float f) {
  union { float f; unsigned u; } a; a.f = f;
  unsigned r = a.u + 0x7fffu + ((a.u >> 16) & 1u);   // RNE
  return (unsigned short)(r >> 16);
}
__device__ __forceinline__ float bf2f(unsigned short h) {
  union { unsigned u; float f; } a; a.u = ((unsigned)h) << 16;
  return a.f;
}

// ---------------------------------------------------------------- router ---
__global__ __launch_bounds__(256) void router_kernel(
    const float* __restrict__ x, const float* __restrict__ Wg,
    int2* __restrict__ topi, float2* __restrict__ topv,
    float* __restrict__ blkimp) {
  __shared__ float wg[NE * DDIM];
  __shared__ float gsh[4][NE];
  int tid = threadIdx.x;
  for (int i = tid; i < NE * DDIM / 4; i += 256)
    ((float4*)wg)[i] = ((const float4*)Wg)[i];
  __syncthreads();
  int w = tid >> 6, lane = tid & 63;
  int t = blockIdx.x * 4 + w;
  const float* xr = x + (size_t)t * DDIM;
  float p[NE] = {0.f, 0.f, 0.f, 0.f, 0.f, 0.f, 0.f, 0.f};
#pragma unroll
  for (int j = 0; j < 16; ++j) {
    float xv = xr[lane + 64 * j];
#pragma unroll
    for (int e = 0; e < NE; ++e)
      p[e] = fmaf(xv, wg[e * DDIM + lane + 64 * j], p[e]);
  }
#pragma unroll
  for (int e = 0; e < NE; ++e) {
#pragma unroll
    for (int off = 32; off > 0; off >>= 1) p[e] += __shfl_xor(p[e], off, 64);
  }
  float mx = p[0];
#pragma unroll
  for (int e = 1; e < NE; ++e) mx = fmaxf(mx, p[e]);
  float g[NE];
  float s = 0.f;
#pragma unroll
  for (int e = 0; e < NE; ++e) { g[e] = expf(p[e] - mx); s += g[e]; }
  float inv = 1.0f / s;
#pragma unroll
  for (int e = 0; e < NE; ++e) g[e] *= inv;
  int i0 = 0; float v0 = g[0];
#pragma unroll
  for (int e = 1; e < NE; ++e) if (g[e] > v0) { v0 = g[e]; i0 = e; }
  int i1 = -1; float v1 = -1.0f;
#pragma unroll
  for (int e = 0; e < NE; ++e)
    if (e != i0 && g[e] > v1) { v1 = g[e]; i1 = e; }
  if (lane == 0) {
    topi[t] = make_int2(i0, i1);
    topv[t] = make_float2(v0, v1);
#pragma unroll
    for (int e = 0; e < NE; ++e) gsh[w][e] = g[e];
  }
  __syncthreads();
  if (tid < NE)
    blkimp[blockIdx.x * NE + tid] =
        gsh[0][tid] + gsh[1][tid] + gsh[2][tid] + gsh[3][tid];
}

// ------------------- FCFS dispatch + losses (hierarchical exact scan) ------
// FCFS rank over slot-major order == segmented prefix-count. 3 phases in one
// block: (A) 4 waves count 64 chunks x 256 entries in parallel; (B) wave-0
// exclusive shfl-prefix over chunk counts per expert (totals -> cnt_sh);
// (C) 4 waves emit ranks = chunk prefix + intra-chunk masked popcount.
// Bit-exact vs the serial scan; deterministic.
__global__ __launch_bounds__(256) void dispatch_kernel(
    const int2* __restrict__ topi, const float2* __restrict__ topv,
    const float* __restrict__ blkimp, int2* __restrict__ posmj,
    float2* __restrict__ wmaj, float* __restrict__ tail) {
  __shared__ unsigned char eid[2 * T_TOK];
  __shared__ unsigned short possm[2 * T_TOK];
  __shared__ int ccnt[64][NE];
  __shared__ int cpre[64][NE];
  __shared__ int cnt_sh[NE];
  __shared__ float part[32][NE];
  int tid = threadIdx.x;
  int w = tid >> 6, lane = tid & 63;
  for (int i = tid; i < T_TOK; i += 256) {
    int2 ti = topi[i];
    eid[i] = (unsigned char)ti.x;
    eid[T_TOK + i] = (unsigned char)ti.y;
  }
  __syncthreads();
  // ---- Phase A: per-chunk per-expert counts (chunks of 256 entries) ----
  for (int ch = w; ch < 64; ch += 4) {
    int c0 = 0, c1 = 0, c2 = 0, c3 = 0, c4 = 0, c5 = 0, c6 = 0, c7 = 0;
    int base = ch * 256;
#pragma unroll
    for (int g2 = 0; g2 < 4; ++g2) {
      int e = eid[base + g2 * 64 + lane];
      c0 += __popcll(__ballot(e == 0));
      c1 += __popcll(__ballot(e == 1));
      c2 += __popcll(__ballot(e == 2));
      c3 += __popcll(__ballot(e == 3));
      c4 += __popcll(__ballot(e == 4));
      c5 += __popcll(__ballot(e == 5));
      c6 += __popcll(__ballot(e == 6));
      c7 += __popcll(__ballot(e == 7));
    }
    if (lane == 0) {
      ccnt[ch][0] = c0; ccnt[ch][1] = c1; ccnt[ch][2] = c2; ccnt[ch][3] = c3;
      ccnt[ch][4] = c4; ccnt[ch][5] = c5; ccnt[ch][6] = c6; ccnt[ch][7] = c7;
    }
  }
  __syncthreads();
  // ---- Phase B: exclusive prefix over 64 chunks, per expert (wave 0) ----
  if (tid < 64) {
#pragma unroll
    for (int e = 0; e < NE; ++e) {
      int own = ccnt[lane][e];
      int inc = own;
#pragma unroll
      for (int off = 1; off < 64; off <<= 1) {
        int tv = __shfl_up(inc, off, 64);
        if (lane >= off) inc += tv;
      }
      cpre[lane][e] = inc - own;
      if (lane == 63) cnt_sh[e] = inc;  // grand total
    }
  }
  __syncthreads();
  // ---- Phase C: emit ranks ----
  {
    unsigned long long low = (1ull << lane) - 1ull;
    for (int ch = w; ch < 64; ch += 4) {
      int r0 = cpre[ch][0], r1 = cpre[ch][1], r2 = cpre[ch][2],
          r3 = cpre[ch][3], r4 = cpre[ch][4], r5 = cpre[ch][5],
          r6 = cpre[ch][6], r7 = cpre[ch][7];
      int base = ch * 256;
#pragma unroll
      for (int g2 = 0; g2 < 4; ++g2) {
        int idx = base + g2 * 64 + lane;
        int e = eid[idx];
        unsigned long long m0 = __ballot(e == 0);
        unsigned long long m1 = __ballot(e == 1);
        unsigned long long m2 = __ballot(e == 2);
        unsigned long long m3 = __ballot(e == 3);
        unsigned long long m4 = __ballot(e == 4);
        unsigned long long m5 = __ballot(e == 5);
        unsigned long long m6 = __ballot(e == 6);
        unsigned long long m7 = __ballot(e == 7);
        int rank = 0;
        if (e == 0) rank = r0 + __popcll(m0 & low);
        if (e == 1) rank = r1 + __popcll(m1 & low);
        if (e == 2) rank = r2 + __popcll(m2 & low);
        if (e == 3) rank = r3 + __popcll(m3 & low);
        if (e == 4) rank = r4 + __popcll(m4 & low);
        if (e == 5) rank = r5 + __popcll(m5 & low);
        if (e == 6) rank = r6 + __popcll(m6 & low);
        if (e == 7) rank = r7 + __popcll(m7 & low);
        possm[idx] = (unsigned short)((rank < CCAP) ? rank : CCAP);
        r0 += __popcll(m0); r1 += __popcll(m1); r2 += __popcll(m2);
        r3 += __popcll(m3); r4 += __popcll(m4); r5 += __popcll(m5);
        r6 += __popcll(m6); r7 += __popcll(m7);
      }
    }
  }
  __syncthreads();
  for (int t = tid; t < T_TOK; t += 256) {
    int p0 = possm[t], p1 = possm[T_TOK + t];
    float2 tv = topv[t];
    float w0 = (p0 < CCAP) ? tv.x : 0.0f;
    float w1 = (p1 < CCAP) ? tv.y : 0.0f;
    float s = w0 + w1;
    if (s > 0.0f) { w0 /= s; w1 /= s; }
    posmj[t] = make_int2(p0, p1);
    wmaj[t] = make_float2(w0, w1);
  }
  {
    int sl = tid >> 3, e8 = tid & 7;
    float s = 0.f;
    for (int b = sl; b < 2048; b += 32) s += blkimp[b * NE + e8];
    part[sl][e8] = s;
  }
  __syncthreads();
  if (tid == 0) {
    float imp[NE], te[NE];
    for (int e = 0; e < NE; ++e) {
      float s = 0.f;
      for (int j = 0; j < 32; ++j) s += part[j][e];
      imp[e] = s;
      int c = cnt_sh[e];
      te[e] = (float)(c < CCAP ? c : CCAP);
    }
    float mi = 0.f, mt = 0.f;
    for (int e = 0; e < NE; ++e) { mi += imp[e]; mt += te[e]; }
    mi *= 0.125f; mt *= 0.125f;
    float vi = 0.f, vt = 0.f;
    for (int e = 0; e < NE; ++e) {
      vi += (imp[e] - mi) * (imp[e] - mi);
      vt += (te[e] - mt) * (te[e] - mt);
    }
    vi *= 0.125f; vt *= 0.125f;
    float ai = sqrtf(vi) / (mi + 1e-6f);
    float at = sqrtf(vt) / (mt + 1e-6f);
    tail[0] = 0.5f * (ai * ai + at * at);
    tail[1] = at * at;
  }
}

// --------------------------------------------------------------- scatter ---
__global__ __launch_bounds__(256) void scatter_kernel(
    const float* __restrict__ x, const int2* __restrict__ topi,
    const int2* __restrict__ posmj, unsigned short* __restrict__ ein) {
  int tid = threadIdx.x;
  int gid = blockIdx.x * 4 + (tid >> 6);
  int lane = tid & 63;
  int t = gid >> 1, k = gid & 1;
  int2 pp = posmj[t];
  int p = k ? pp.y : pp.x;
  if (p >= CCAP) return;
  int2 ii = topi[t];
  int e = k ? ii.y : ii.x;
  const float4* src = (const float4*)(x + (size_t)t * DDIM);
  unsigned short* dst = ein + ((size_t)e * CPAD + p) * DDIM;
#pragma unroll
  for (int j = 0; j < 4; ++j) {
    int c = j * 64 + lane;
    float4 v = src[c];
    ushort4v o;
    o.x = f2bf(v.x); o.y = f2bf(v.y); o.z = f2bf(v.z); o.w = f2bf(v.w);
    *(ushort4v*)(dst + (size_t)c * 4) = o;
  }
}

// ------------------------------------------------- weight transpose+cvt ----
__global__ __launch_bounds__(256) void transpose_cvt_kernel(
    const float* __restrict__ W, unsigned short* __restrict__ WT, int R,
    int Cc) {
  __shared__ unsigned short tile[64][72];
  int rt = R >> 6, ct = Cc >> 6;
  int per_e = rt * ct;
  int e = blockIdx.x / per_e;
  int rem = blockIdx.x % per_e;
  int tr = rem % rt, tc = rem / rt;
  int r0 = tr << 6, c0 = tc << 6;
  const float* We = W + (size_t)e * R * Cc;
  unsigned short* WTe = WT + (size_t)e * R * Cc;
  int tid = threadIdx.x;
  {
    int rl = tid >> 2, cb = (tid & 3) << 4;
    const float* src = We + (size_t)(r0 + rl) * Cc + c0 + cb;
#pragma unroll
    for (int j = 0; j < 16; j += 4) {
      float4 v = *(const float4*)(src + j);
      tile[rl][cb + j + 0] = f2bf(v.x);
      tile[rl][cb + j + 1] = f2bf(v.y);
      tile[rl][cb + j + 2] = f2bf(v.z);
      tile[rl][cb + j + 3] = f2bf(v.w);
    }
  }
  __syncthreads();
  {
    int cl = tid >> 2, rb = (tid & 3) << 4;
    unsigned short* dst = WTe + (size_t)(c0 + cl) * R + r0 + rb;
#pragma unroll
    for (int j = 0; j < 16; j += 4) {
      ushort4v o;
      o.x = tile[rb + j + 0][cl];
      o.y = tile[rb + j + 1][cl];
      o.z = tile[rb + j + 2][cl];
      o.w = tile[rb + j + 3][cl];
      *(ushort4v*)(dst + j) = o;
    }
  }
}

// ----------------------- 256x256 GEMM, REG-STAGED (best measured) ----------
template <bool GELU>
__global__ __launch_bounds__(512, 2) void gemm256_rs(
    const unsigned short* __restrict__ A, const unsigned short* __restrict__ B,
    const float* __restrict__ bias, unsigned short* __restrict__ Out0,
    unsigned short* __restrict__ Out1, int M, int N, int Kz, int Ksub, int NT,
    int mt, int nt) {
  __shared__ __align__(16) char smem[131072];
  int nwg = gridDim.x;
  int bid = blockIdx.x;
  int swz = (bid & 7) * (nwg >> 3) + (bid >> 3);  // XCD-aware (nwg % 8 == 0)
  int bm = swz % mt;
  int r = swz / mt;
  int bn = r % nt;
  int r2 = r / nt;
  int e = r2 & 7;
  int ks = r2 >> 3;
  unsigned short* Outp = ks ? Out1 : Out0;
  int koff = ks * Ksub;

  int tid = threadIdx.x;
  int w = tid >> 6, lane = tid & 63;
  int wm = w >> 2, wn = w & 3;
  int fr = lane & 15, g = lane >> 4;
  size_t Kzs = (size_t)Kz;
  const char* Ab = (const char*)(A + ((size_t)e * M + (size_t)bm * 256) * Kzs + koff);
  const char* Bb = (const char*)(B + ((size_t)e * N + (size_t)bn * 256) * Kzs + koff);

  size_t ro0 = (size_t)(w * 16 + fr) * Kzs * 2 + (size_t)g * 16;
  size_t ro1 = ro0 + (size_t)128 * Kzs * 2;
  int ld0 = (w << 10) + lane * 16;
  int ld1 = ((8 + w) << 10) + lane * 16;

  short8v st[8];
  auto gload = [&](const char* a, const char* b) {
    st[0] = *(const short8v*)(a + ro0);
    st[1] = *(const short8v*)(a + ro1);
    st[2] = *(const short8v*)(a + ro0 + 64);
    st[3] = *(const short8v*)(a + ro1 + 64);
    st[4] = *(const short8v*)(b + ro0);
    st[5] = *(const short8v*)(b + ro1);
    st[6] = *(const short8v*)(b + ro0 + 64);
    st[7] = *(const short8v*)(b + ro1 + 64);
  };
  auto swrite = [&](int buf) {
    char* p = smem + (buf << 15);
    *(short8v*)(p + ld0) = st[0];
    *(short8v*)(p + ld1) = st[1];
    *(short8v*)(p + 16384 + ld0) = st[2];
    *(short8v*)(p + 16384 + ld1) = st[3];
    *(short8v*)(p + 65536 + ld0) = st[4];
    *(short8v*)(p + 65536 + ld1) = st[5];
    *(short8v*)(p + 65536 + 16384 + ld0) = st[6];
    *(short8v*)(p + 65536 + 16384 + ld1) = st[7];
  };
  auto lda = [&](int buf, int kk, int m16) -> short8v {
    return *(const short8v*)(smem + (buf << 15) + (kk << 14) + (m16 << 10) +
                             lane * 16);
  };
  auto ldb = [&](int buf, int kk, int n16) -> short8v {
    return *(const short8v*)(smem + 65536 + (buf << 15) + (kk << 14) +
                             (n16 << 10) + lane * 16);
  };

  f32x4 acc[8][4] = {};

  // prologue: tile0 -> LDS buf0; tile1 -> regs
  gload(Ab, Bb);
  swrite(0);
  gload(Ab + 128, Bb + 128);
  __syncthreads();

  for (int t = 0; t < NT; ++t) {
    int c = t & 1;
#pragma unroll
    for (int kk = 0; kk < 2; ++kk) {
      short8v bv4[4], av;
#pragma unroll
      for (int n = 0; n < 4; ++n) bv4[n] = ldb(c, kk, wn * 4 + n);
#pragma unroll
      for (int m = 0; m < 8; ++m) {
        av = lda(c, kk, wm * 8 + m);
#pragma unroll
        for (int n = 0; n < 4; ++n)
          acc[m][n] = __builtin_amdgcn_mfma_f32_16x16x32_bf16(av, bv4[n],
                                                              acc[m][n], 0, 0, 0);
      }
    }
    if (t + 1 < NT) swrite(c ^ 1);
    if (t + 2 < NT)
      gload(Ab + (size_t)(t + 2) * 128, Bb + (size_t)(t + 2) * 128);
    __syncthreads();
  }

  // ---- epilogue: bias/GELU -> per-wave LDS bounce -> coalesced stores ----
  float bv[4];
#pragma unroll
  for (int n = 0; n < 4; ++n)
    bv[n] = (ks == 0)
                ? bias[(size_t)e * N + (size_t)bn * 256 + wn * 64 + n * 16 + fr]
                : 0.0f;
  char* wreg = smem + w * 16384;
#pragma unroll
  for (int m = 0; m < 8; ++m)
#pragma unroll
    for (int n = 0; n < 4; ++n)
#pragma unroll
      for (int j = 0; j < 4; ++j) {
        float v = acc[m][n][j] + bv[n];
        if (GELU) v = 0.5f * v * (1.0f + erff(v * 0.70710678118654752f));
        int rl = m * 16 + g * 4 + j;
        *(unsigned short*)(wreg + rl * 128 + (n * 16 + fr) * 2) = f2bf(v);
      }
  unsigned short* Oe = Outp +
                       ((size_t)e * M + (size_t)bm * 256 + (size_t)wm * 128) * N +
                       (size_t)bn * 256 + (size_t)wn * 64;
#pragma unroll
  for (int pass = 0; pass < 16; ++pass) {
    int rr = pass * 8 + (lane >> 3);
    int ch = lane & 7;
    short8v vv = *(const short8v*)(wreg + rr * 128 + ch * 16);
    *(short8v*)(Oe + (size_t)rr * N + ch * 8) = vv;
  }
}

// ---------------------------------------------------------------- gather ---
__global__ __launch_bounds__(256) void gather_kernel(
    const unsigned short* __restrict__ obufA,
    const unsigned short* __restrict__ obufB, const int2* __restrict__ topi,
    const int2* __restrict__ posmj, const float2* __restrict__ wmaj,
    float* __restrict__ y) {
  int tid = threadIdx.x;
  int w = tid >> 6, lane = tid & 63;
  int t = blockIdx.x * 4 + w;
  int2 pp = posmj[t];
  int2 ii = topi[t];
  float2 ww = wmaj[t];
  float* yr = y + (size_t)t * DDIM;
  size_t o0 = ((size_t)ii.x * CPAD + pp.x) * DDIM;
  size_t o1 = ((size_t)ii.y * CPAD + pp.y) * DDIM;
  bool v0 = pp.x < CCAP, v1 = pp.y < CCAP;
#pragma unroll
  for (int j = 0; j < 4; ++j) {
    int c = j * 64 + lane;
    float ax = 0.f, ay = 0.f, az = 0.f, aw = 0.f;
    if (v0) {
      ushort4v a = *(const ushort4v*)(obufA + o0 + (size_t)c * 4);
      ushort4v b = *(const ushort4v*)(obufB + o0 + (size_t)c * 4);
      ax += ww.x * (bf2f(a.x) + bf2f(b.x));
      ay += ww.x * (bf2f(a.y) + bf2f(b.y));
      az += ww.x * (bf2f(a.z) + bf2f(b.z));
      aw += ww.x * (bf2f(a.w) + bf2f(b.w));
    }
    if (v1) {
      ushort4v a = *(const ushort4v*)(obufA + o1 + (size_t)c * 4);
      ushort4v b = *(const ushort4v*)(obufB + o1 + (size_t)c * 4);
      ax += ww.y * (bf2f(a.x) + bf2f(b.x));
      ay += ww.y * (bf2f(a.y) + bf2f(b.y));
      az += ww.y * (bf2f(a.z) + bf2f(b.z));
      aw += ww.y * (bf2f(a.w) + bf2f(b.w));
    }
    ((float4*)yr)[c] = make_float4(ax, ay, az, aw);
  }
}

// ---------------------------------------------------------------------------
extern "C" void kernel_launch(void* const* d_in, const int* in_sizes, int n_in,
                              void* d_out, int out_size, void* d_ws,
                              size_t ws_size, hipStream_t stream) {
  (void)in_sizes; (void)n_in; (void)out_size; (void)ws_size;
  const float* x = (const float*)d_in[0];
  const float* Wg = (const float*)d_in[1];
  const float* W1 = (const float*)d_in[2];
  const float* b1 = (const float*)d_in[3];
  const float* W2 = (const float*)d_in[4];
  const float* b2 = (const float*)d_in[5];
  float* out = (float*)d_out;

  char* ws = (char*)d_ws;
  size_t off = 0;
  auto alloc = [&](size_t b) {
    char* p = ws + off;
    off += (b + 255) & ~(size_t)255;
    return p;
  };
  unsigned short* ein = (unsigned short*)alloc((size_t)NE * CPAD * DDIM * 2);
  unsigned short* hbuf = (unsigned short*)alloc((size_t)NE * CPAD * HDIM * 2);
  unsigned short* obuf = (unsigned short*)alloc((size_t)NE * CPAD * DDIM * 2);
  unsigned short* w1t = (unsigned short*)alloc((size_t)NE * HDIM * DDIM * 2);
  unsigned short* w2t = (unsigned short*)alloc((size_t)NE * DDIM * HDIM * 2);
  int2* topi = (int2*)alloc(T_TOK * sizeof(int2));
  float2* topv = (float2*)alloc(T_TOK * sizeof(float2));
  int2* posmj = (int2*)alloc(T_TOK * sizeof(int2));
  float2* wmaj = (float2*)alloc(T_TOK * sizeof(float2));
  float* blkimp = (float*)alloc(2048 * NE * sizeof(float));

  transpose_cvt_kernel<<<NE * (DDIM / 64) * (HDIM / 64), 256, 0, stream>>>(
      W1, w1t, DDIM, HDIM);
  transpose_cvt_kernel<<<NE * (HDIM / 64) * (DDIM / 64), 256, 0, stream>>>(
      W2, w2t, HDIM, DDIM);
  router_kernel<<<T_TOK / 4, 256, 0, stream>>>(x, Wg, topi, topv, blkimp);
  dispatch_kernel<<<1, 256, 0, stream>>>(topi, topv, blkimp, posmj, wmaj,
                                         out + (size_t)T_TOK * DDIM);
  scatter_kernel<<<(2 * T_TOK) / 4, 256, 0, stream>>>(x, topi, posmj, ein);

  // gemm1: (E,2304,1024) x (E,4096,1024)^T -> hbuf, GELU+b1 (reg-staged)
  gemm256_rs<true><<<NE * 9 * 16, 512, 0, stream>>>(
      ein, w1t, b1, hbuf, hbuf, CPAD, HDIM, DDIM, DDIM, DDIM / 64, 9, 16);
  // gemm2: (E,2304,4096) x (E,1024,4096)^T -> obuf (+b2) and ein (split-K=2)
  gemm256_rs<false><<<NE * 9 * 4 * 2, 512, 0, stream>>>(
      hbuf, w2t, b2, obuf, ein, CPAD, DDIM, HDIM, HDIM / 2, HDIM / 128, 9, 4);

  gather_kernel<<<T_TOK / 4, 256, 0, stream>>>(obuf, ein, topi, posmj, wmaj,
                                               out);
}

// Round 22
// 638.438 us; speedup vs baseline: 1.0017x; 1.0017x over previous
//
#include <hip/hip_runtime.h>
#include <math.h>

typedef short short8v __attribute__((ext_vector_type(8)));
typedef float f32x4 __attribute__((ext_vector_type(4)));
typedef unsigned short ushort4v __attribute__((ext_vector_type(4)));

#define T_TOK 8192
#define DDIM 1024
#define HDIM 4096
#define NE 8
#define CCAP 2150
#define CPAD 2304   // 9 * 256

__device__ __forceinline__ unsigned short f2bf(float f) {
  union { float f; unsigned u; } a; a.f = f;
  unsigned r = a.u + 0x7fffu + ((a.u >> 16) & 1u);   // RNE
  return (unsigned short)(r >> 16);
}
__device__ __forceinline__ float bf2f(unsigned short h) {
  union { unsigned u; float f; } a; a.u = ((unsigned)h) << 16;
  return a.f;
}

// ---------------------------------------------------------------- router ---
__global__ __launch_bounds__(256) void router_kernel(
    const float* __restrict__ x, const float* __restrict__ Wg,
    int2* __restrict__ topi, float2* __restrict__ topv,
    float* __restrict__ blkimp) {
  __shared__ float wg[NE * DDIM];
  __shared__ float gsh[4][NE];
  int tid = threadIdx.x;
  for (int i = tid; i < NE * DDIM / 4; i += 256)
    ((float4*)wg)[i] = ((const float4*)Wg)[i];
  __syncthreads();
  int w = tid >> 6, lane = tid & 63;
  int t = blockIdx.x * 4 + w;
  const float* xr = x + (size_t)t * DDIM;
  float p[NE] = {0.f, 0.f, 0.f, 0.f, 0.f, 0.f, 0.f, 0.f};
#pragma unroll
  for (int j = 0; j < 16; ++j) {
    float xv = xr[lane + 64 * j];
#pragma unroll
    for (int e = 0; e < NE; ++e)
      p[e] = fmaf(xv, wg[e * DDIM + lane + 64 * j], p[e]);
  }
#pragma unroll
  for (int e = 0; e < NE; ++e) {
#pragma unroll
    for (int off = 32; off > 0; off >>= 1) p[e] += __shfl_xor(p[e], off, 64);
  }
  float mx = p[0];
#pragma unroll
  for (int e = 1; e < NE; ++e) mx = fmaxf(mx, p[e]);
  float g[NE];
  float s = 0.f;
#pragma unroll
  for (int e = 0; e < NE; ++e) { g[e] = expf(p[e] - mx); s += g[e]; }
  float inv = 1.0f / s;
#pragma unroll
  for (int e = 0; e < NE; ++e) g[e] *= inv;
  int i0 = 0; float v0 = g[0];
#pragma unroll
  for (int e = 1; e < NE; ++e) if (g[e] > v0) { v0 = g[e]; i0 = e; }
  int i1 = -1; float v1 = -1.0f;
#pragma unroll
  for (int e = 0; e < NE; ++e)
    if (e != i0 && g[e] > v1) { v1 = g[e]; i1 = e; }
  if (lane == 0) {
    topi[t] = make_int2(i0, i1);
    topv[t] = make_float2(v0, v1);
#pragma unroll
    for (int e = 0; e < NE; ++e) gsh[w][e] = g[e];
  }
  __syncthreads();
  if (tid < NE)
    blkimp[blockIdx.x * NE + tid] =
        gsh[0][tid] + gsh[1][tid] + gsh[2][tid] + gsh[3][tid];
}

// ------------------- FCFS dispatch + losses (hierarchical exact scan) ------
// FCFS rank over slot-major order == segmented prefix-count. 3 phases in one
// block: (A) 4 waves count 64 chunks x 256 entries in parallel; (B) wave-0
// exclusive shfl-prefix over chunk counts per expert (totals -> cnt_sh);
// (C) 4 waves emit ranks = chunk prefix + intra-chunk masked popcount.
// Bit-exact vs the serial scan; deterministic.
__global__ __launch_bounds__(256) void dispatch_kernel(
    const int2* __restrict__ topi, const float2* __restrict__ topv,
    const float* __restrict__ blkimp, int2* __restrict__ posmj,
    float2* __restrict__ wmaj, float* __restrict__ tail) {
  __shared__ unsigned char eid[2 * T_TOK];
  __shared__ unsigned short possm[2 * T_TOK];
  __shared__ int ccnt[64][NE];
  __shared__ int cpre[64][NE];
  __shared__ int cnt_sh[NE];
  __shared__ float part[32][NE];
  int tid = threadIdx.x;
  int w = tid >> 6, lane = tid & 63;
  for (int i = tid; i < T_TOK; i += 256) {
    int2 ti = topi[i];
    eid[i] = (unsigned char)ti.x;
    eid[T_TOK + i] = (unsigned char)ti.y;
  }
  __syncthreads();
  // ---- Phase A: per-chunk per-expert counts (chunks of 256 entries) ----
  for (int ch = w; ch < 64; ch += 4) {
    int c0 = 0, c1 = 0, c2 = 0, c3 = 0, c4 = 0, c5 = 0, c6 = 0, c7 = 0;
    int base = ch * 256;
#pragma unroll
    for (int g2 = 0; g2 < 4; ++g2) {
      int e = eid[base + g2 * 64 + lane];
      c0 += __popcll(__ballot(e == 0));
      c1 += __popcll(__ballot(e == 1));
      c2 += __popcll(__ballot(e == 2));
      c3 += __popcll(__ballot(e == 3));
      c4 += __popcll(__ballot(e == 4));
      c5 += __popcll(__ballot(e == 5));
      c6 += __popcll(__ballot(e == 6));
      c7 += __popcll(__ballot(e == 7));
    }
    if (lane == 0) {
      ccnt[ch][0] = c0; ccnt[ch][1] = c1; ccnt[ch][2] = c2; ccnt[ch][3] = c3;
      ccnt[ch][4] = c4; ccnt[ch][5] = c5; ccnt[ch][6] = c6; ccnt[ch][7] = c7;
    }
  }
  __syncthreads();
  // ---- Phase B: exclusive prefix over 64 chunks, per expert (wave 0) ----
  if (tid < 64) {
#pragma unroll
    for (int e = 0; e < NE; ++e) {
      int own = ccnt[lane][e];
      int inc = own;
#pragma unroll
      for (int off = 1; off < 64; off <<= 1) {
        int tv = __shfl_up(inc, off, 64);
        if (lane >= off) inc += tv;
      }
      cpre[lane][e] = inc - own;
      if (lane == 63) cnt_sh[e] = inc;  // grand total
    }
  }
  __syncthreads();
  // ---- Phase C: emit ranks ----
  {
    unsigned long long low = (1ull << lane) - 1ull;
    for (int ch = w; ch < 64; ch += 4) {
      int r0 = cpre[ch][0], r1 = cpre[ch][1], r2 = cpre[ch][2],
          r3 = cpre[ch][3], r4 = cpre[ch][4], r5 = cpre[ch][5],
          r6 = cpre[ch][6], r7 = cpre[ch][7];
      int base = ch * 256;
#pragma unroll
      for (int g2 = 0; g2 < 4; ++g2) {
        int idx = base + g2 * 64 + lane;
        int e = eid[idx];
        unsigned long long m0 = __ballot(e == 0);
        unsigned long long m1 = __ballot(e == 1);
        unsigned long long m2 = __ballot(e == 2);
        unsigned long long m3 = __ballot(e == 3);
        unsigned long long m4 = __ballot(e == 4);
        unsigned long long m5 = __ballot(e == 5);
        unsigned long long m6 = __ballot(e == 6);
        unsigned long long m7 = __ballot(e == 7);
        int rank = 0;
        if (e == 0) rank = r0 + __popcll(m0 & low);
        if (e == 1) rank = r1 + __popcll(m1 & low);
        if (e == 2) rank = r2 + __popcll(m2 & low);
        if (e == 3) rank = r3 + __popcll(m3 & low);
        if (e == 4) rank = r4 + __popcll(m4 & low);
        if (e == 5) rank = r5 + __popcll(m5 & low);
        if (e == 6) rank = r6 + __popcll(m6 & low);
        if (e == 7) rank = r7 + __popcll(m7 & low);
        possm[idx] = (unsigned short)((rank < CCAP) ? rank : CCAP);
        r0 += __popcll(m0); r1 += __popcll(m1); r2 += __popcll(m2);
        r3 += __popcll(m3); r4 += __popcll(m4); r5 += __popcll(m5);
        r6 += __popcll(m6); r7 += __popcll(m7);
      }
    }
  }
  __syncthreads();
  for (int t = tid; t < T_TOK; t += 256) {
    int p0 = possm[t], p1 = possm[T_TOK + t];
    float2 tv = topv[t];
    float w0 = (p0 < CCAP) ? tv.x : 0.0f;
    float w1 = (p1 < CCAP) ? tv.y : 0.0f;
    float s = w0 + w1;
    if (s > 0.0f) { w0 /= s; w1 /= s; }
    posmj[t] = make_int2(p0, p1);
    wmaj[t] = make_float2(w0, w1);
  }
  {
    int sl = tid >> 3, e8 = tid & 7;
    float s = 0.f;
    for (int b = sl; b < 2048; b += 32) s += blkimp[b * NE + e8];
    part[sl][e8] = s;
  }
  __syncthreads();
  if (tid == 0) {
    float imp[NE], te[NE];
    for (int e = 0; e < NE; ++e) {
      float s = 0.f;
      for (int j = 0; j < 32; ++j) s += part[j][e];
      imp[e] = s;
      int c = cnt_sh[e];
      te[e] = (float)(c < CCAP ? c : CCAP);
    }
    float mi = 0.f, mt = 0.f;
    for (int e = 0; e < NE; ++e) { mi += imp[e]; mt += te[e]; }
    mi *= 0.125f; mt *= 0.125f;
    float vi = 0.f, vt = 0.f;
    for (int e = 0; e < NE; ++e) {
      vi += (imp[e] - mi) * (imp[e] - mi);
      vt += (te[e] - mt) * (te[e] - mt);
    }
    vi *= 0.125f; vt *= 0.125f;
    float ai = sqrtf(vi) / (mi + 1e-6f);
    float at = sqrtf(vt) / (mt + 1e-6f);
    tail[0] = 0.5f * (ai * ai + at * at);
    tail[1] = at * at;
  }
}

// --------------------------------------------------------------- scatter ---
__global__ __launch_bounds__(256) void scatter_kernel(
    const float* __restrict__ x, const int2* __restrict__ topi,
    const int2* __restrict__ posmj, unsigned short* __restrict__ ein) {
  int tid = threadIdx.x;
  int gid = blockIdx.x * 4 + (tid >> 6);
  int lane = tid & 63;
  int t = gid >> 1, k = gid & 1;
  int2 pp = posmj[t];
  int p = k ? pp.y : pp.x;
  if (p >= CCAP) return;
  int2 ii = topi[t];
  int e = k ? ii.y : ii.x;
  const float4* src = (const float4*)(x + (size_t)t * DDIM);
  unsigned short* dst = ein + ((size_t)e * CPAD + p) * DDIM;
#pragma unroll
  for (int j = 0; j < 4; ++j) {
    int c = j * 64 + lane;
    float4 v = src[c];
    ushort4v o;
    o.x = f2bf(v.x); o.y = f2bf(v.y); o.z = f2bf(v.z); o.w = f2bf(v.w);
    *(ushort4v*)(dst + (size_t)c * 4) = o;
  }
}

// ------------------------------------------------- weight transpose+cvt ----
__global__ __launch_bounds__(256) void transpose_cvt_kernel(
    const float* __restrict__ W, unsigned short* __restrict__ WT, int R,
    int Cc) {
  __shared__ unsigned short tile[64][72];
  int rt = R >> 6, ct = Cc >> 6;
  int per_e = rt * ct;
  int e = blockIdx.x / per_e;
  int rem = blockIdx.x % per_e;
  int tr = rem % rt, tc = rem / rt;
  int r0 = tr << 6, c0 = tc << 6;
  const float* We = W + (size_t)e * R * Cc;
  unsigned short* WTe = WT + (size_t)e * R * Cc;
  int tid = threadIdx.x;
  {
    int rl = tid >> 2, cb = (tid & 3) << 4;
    const float* src = We + (size_t)(r0 + rl) * Cc + c0 + cb;
#pragma unroll
    for (int j = 0; j < 16; j += 4) {
      float4 v = *(const float4*)(src + j);
      tile[rl][cb + j + 0] = f2bf(v.x);
      tile[rl][cb + j + 1] = f2bf(v.y);
      tile[rl][cb + j + 2] = f2bf(v.z);
      tile[rl][cb + j + 3] = f2bf(v.w);
    }
  }
  __syncthreads();
  {
    int cl = tid >> 2, rb = (tid & 3) << 4;
    unsigned short* dst = WTe + (size_t)(c0 + cl) * R + r0 + rb;
#pragma unroll
    for (int j = 0; j < 16; j += 4) {
      ushort4v o;
      o.x = tile[rb + j + 0][cl];
      o.y = tile[rb + j + 1][cl];
      o.z = tile[rb + j + 2][cl];
      o.w = tile[rb + j + 3][cl];
      *(ushort4v*)(dst + j) = o;
    }
  }
}

// ----------------------- 256x256 GEMM, REG-STAGED (best measured) ----------
template <bool GELU>
__global__ __launch_bounds__(512, 2) void gemm256_rs(
    const unsigned short* __restrict__ A, const unsigned short* __restrict__ B,
    const float* __restrict__ bias, unsigned short* __restrict__ Out0,
    unsigned short* __restrict__ Out1, int M, int N, int Kz, int Ksub, int NT,
    int mt, int nt) {
  __shared__ __align__(16) char smem[131072];
  int nwg = gridDim.x;
  int bid = blockIdx.x;
  int swz = (bid & 7) * (nwg >> 3) + (bid >> 3);  // XCD-aware (nwg % 8 == 0)
  int bm = swz % mt;
  int r = swz / mt;
  int bn = r % nt;
  int r2 = r / nt;
  int e = r2 & 7;
  int ks = r2 >> 3;
  unsigned short* Outp = ks ? Out1 : Out0;
  int koff = ks * Ksub;

  int tid = threadIdx.x;
  int w = tid >> 6, lane = tid & 63;
  int wm = w >> 2, wn = w & 3;
  int fr = lane & 15, g = lane >> 4;
  size_t Kzs = (size_t)Kz;
  const char* Ab = (const char*)(A + ((size_t)e * M + (size_t)bm * 256) * Kzs + koff);
  const char* Bb = (const char*)(B + ((size_t)e * N + (size_t)bn * 256) * Kzs + koff);

  size_t ro0 = (size_t)(w * 16 + fr) * Kzs * 2 + (size_t)g * 16;
  size_t ro1 = ro0 + (size_t)128 * Kzs * 2;
  int ld0 = (w << 10) + lane * 16;
  int ld1 = ((8 + w) << 10) + lane * 16;

  short8v st[8];
  auto gload = [&](const char* a, const char* b) {
    st[0] = *(const short8v*)(a + ro0);
    st[1] = *(const short8v*)(a + ro1);
    st[2] = *(const short8v*)(a + ro0 + 64);
    st[3] = *(const short8v*)(a + ro1 + 64);
    st[4] = *(const short8v*)(b + ro0);
    st[5] = *(const short8v*)(b + ro1);
    st[6] = *(const short8v*)(b + ro0 + 64);
    st[7] = *(const short8v*)(b + ro1 + 64);
  };
  auto swrite = [&](int buf) {
    char* p = smem + (buf << 15);
    *(short8v*)(p + ld0) = st[0];
    *(short8v*)(p + ld1) = st[1];
    *(short8v*)(p + 16384 + ld0) = st[2];
    *(short8v*)(p + 16384 + ld1) = st[3];
    *(short8v*)(p + 65536 + ld0) = st[4];
    *(short8v*)(p + 65536 + ld1) = st[5];
    *(short8v*)(p + 65536 + 16384 + ld0) = st[6];
    *(short8v*)(p + 65536 + 16384 + ld1) = st[7];
  };
  auto lda = [&](int buf, int kk, int m16) -> short8v {
    return *(const short8v*)(smem + (buf << 15) + (kk << 14) + (m16 << 10) +
                             lane * 16);
  };
  auto ldb = [&](int buf, int kk, int n16) -> short8v {
    return *(const short8v*)(smem + 65536 + (buf << 15) + (kk << 14) +
                             (n16 << 10) + lane * 16);
  };

  f32x4 acc[8][4] = {};

  // prologue: tile0 -> LDS buf0; tile1 -> regs
  gload(Ab, Bb);
  swrite(0);
  gload(Ab + 128, Bb + 128);
  __syncthreads();

  for (int t = 0; t < NT; ++t) {
    int c = t & 1;
#pragma unroll
    for (int kk = 0; kk < 2; ++kk) {
      short8v bv4[4], av;
#pragma unroll
      for (int n = 0; n < 4; ++n) bv4[n] = ldb(c, kk, wn * 4 + n);
#pragma unroll
      for (int m = 0; m < 8; ++m) {
        av = lda(c, kk, wm * 8 + m);
#pragma unroll
        for (int n = 0; n < 4; ++n)
          acc[m][n] = __builtin_amdgcn_mfma_f32_16x16x32_bf16(av, bv4[n],
                                                              acc[m][n], 0, 0, 0);
      }
    }
    if (t + 1 < NT) swrite(c ^ 1);
    if (t + 2 < NT)
      gload(Ab + (size_t)(t + 2) * 128, Bb + (size_t)(t + 2) * 128);
    __syncthreads();
  }

  // ---- epilogue: bias/GELU -> per-wave LDS bounce -> coalesced stores ----
  float bv[4];
#pragma unroll
  for (int n = 0; n < 4; ++n)
    bv[n] = (ks == 0)
                ? bias[(size_t)e * N + (size_t)bn * 256 + wn * 64 + n * 16 + fr]
                : 0.0f;
  char* wreg = smem + w * 16384;
#pragma unroll
  for (int m = 0; m < 8; ++m)
#pragma unroll
    for (int n = 0; n < 4; ++n)
#pragma unroll
      for (int j = 0; j < 4; ++j) {
        float v = acc[m][n][j] + bv[n];
        if (GELU) v = 0.5f * v * (1.0f + erff(v * 0.70710678118654752f));
        int rl = m * 16 + g * 4 + j;
        *(unsigned short*)(wreg + rl * 128 + (n * 16 + fr) * 2) = f2bf(v);
      }
  unsigned short* Oe = Outp +
                       ((size_t)e * M + (size_t)bm * 256 + (size_t)wm * 128) * N +
                       (size_t)bn * 256 + (size_t)wn * 64;
#pragma unroll
  for (int pass = 0; pass < 16; ++pass) {
    int rr = pass * 8 + (lane >> 3);
    int ch = lane & 7;
    short8v vv = *(const short8v*)(wreg + rr * 128 + ch * 16);
    *(short8v*)(Oe + (size_t)rr * N + ch * 8) = vv;
  }
}

// ---------------------------------------------------------------- gather ---
__global__ __launch_bounds__(256) void gather_kernel(
    const unsigned short* __restrict__ obufA,
    const unsigned short* __restrict__ obufB, const int2* __restrict__ topi,
    const int2* __restrict__ posmj, const float2* __restrict__ wmaj,
    float* __restrict__ y) {
  int tid = threadIdx.x;
  int w = tid >> 6, lane = tid & 63;
  int t = blockIdx.x * 4 + w;
  int2 pp = posmj[t];
  int2 ii = topi[t];
  float2 ww = wmaj[t];
  float* yr = y + (size_t)t * DDIM;
  size_t o0 = ((size_t)ii.x * CPAD + pp.x) * DDIM;
  size_t o1 = ((size_t)ii.y * CPAD + pp.y) * DDIM;
  bool v0 = pp.x < CCAP, v1 = pp.y < CCAP;
#pragma unroll
  for (int j = 0; j < 4; ++j) {
    int c = j * 64 + lane;
    float ax = 0.f, ay = 0.f, az = 0.f, aw = 0.f;
    if (v0) {
      ushort4v a = *(const ushort4v*)(obufA + o0 + (size_t)c * 4);
      ushort4v b = *(const ushort4v*)(obufB + o0 + (size_t)c * 4);
      ax += ww.x * (bf2f(a.x) + bf2f(b.x));
      ay += ww.x * (bf2f(a.y) + bf2f(b.y));
      az += ww.x * (bf2f(a.z) + bf2f(b.z));
      aw += ww.x * (bf2f(a.w) + bf2f(b.w));
    }
    if (v1) {
      ushort4v a = *(const ushort4v*)(obufA + o1 + (size_t)c * 4);
      ushort4v b = *(const ushort4v*)(obufB + o1 + (size_t)c * 4);
      ax += ww.y * (bf2f(a.x) + bf2f(b.x));
      ay += ww.y * (bf2f(a.y) + bf2f(b.y));
      az += ww.y * (bf2f(a.z) + bf2f(b.z));
      aw += ww.y * (bf2f(a.w) + bf2f(b.w));
    }
    ((float4*)yr)[c] = make_float4(ax, ay, az, aw);
  }
}

// ---------------------------------------------------------------------------
extern "C" void kernel_launch(void* const* d_in, const int* in_sizes, int n_in,
                              void* d_out, int out_size, void* d_ws,
                              size_t ws_size, hipStream_t stream) {
  (void)in_sizes; (void)n_in; (void)out_size; (void)ws_size;
  const float* x = (const float*)d_in[0];
  const float* Wg = (const float*)d_in[1];
  const float* W1 = (const float*)d_in[2];
  const float* b1 = (const float*)d_in[3];
  const float* W2 = (const float*)d_in[4];
  const float* b2 = (const float*)d_in[5];
  float* out = (float*)d_out;

  char* ws = (char*)d_ws;
  size_t off = 0;
  auto alloc = [&](size_t b) {
    char* p = ws + off;
    off += (b + 255) & ~(size_t)255;
    return p;
  };
  unsigned short* ein = (unsigned short*)alloc((size_t)NE * CPAD * DDIM * 2);
  unsigned short* hbuf = (unsigned short*)alloc((size_t)NE * CPAD * HDIM * 2);
  unsigned short* obuf = (unsigned short*)alloc((size_t)NE * CPAD * DDIM * 2);
  unsigned short* w1t = (unsigned short*)alloc((size_t)NE * HDIM * DDIM * 2);
  unsigned short* w2t = (unsigned short*)alloc((size_t)NE * DDIM * HDIM * 2);
  int2* topi = (int2*)alloc(T_TOK * sizeof(int2));
  float2* topv = (float2*)alloc(T_TOK * sizeof(float2));
  int2* posmj = (int2*)alloc(T_TOK * sizeof(int2));
  float2* wmaj = (float2*)alloc(T_TOK * sizeof(float2));
  float* blkimp = (float*)alloc(2048 * NE * sizeof(float));

  transpose_cvt_kernel<<<NE * (DDIM / 64) * (HDIM / 64), 256, 0, stream>>>(
      W1, w1t, DDIM, HDIM);
  transpose_cvt_kernel<<<NE * (HDIM / 64) * (DDIM / 64), 256, 0, stream>>>(
      W2, w2t, HDIM, DDIM);
  router_kernel<<<T_TOK / 4, 256, 0, stream>>>(x, Wg, topi, topv, blkimp);
  dispatch_kernel<<<1, 256, 0, stream>>>(topi, topv, blkimp, posmj, wmaj,
                                         out + (size_t)T_TOK * DDIM);
  scatter_kernel<<<(2 * T_TOK) / 4, 256, 0, stream>>>(x, topi, posmj, ein);

  // gemm1: (E,2304,1024) x (E,4096,1024)^T -> hbuf, GELU+b1 (reg-staged)
  gemm256_rs<true><<<NE * 9 * 16, 512, 0, stream>>>(
      ein, w1t, b1, hbuf, hbuf, CPAD, HDIM, DDIM, DDIM, DDIM / 64, 9, 16);
  // gemm2: (E,2304,4096) x (E,1024,4096)^T -> obuf (+b2) and ein (split-K=2)
  gemm256_rs<false><<<NE * 9 * 4 * 2, 512, 0, stream>>>(
      hbuf, w2t, b2, obuf, ein, CPAD, DDIM, HDIM, HDIM / 2, HDIM / 128, 9, 4);

  gather_kernel<<<T_TOK / 4, 256, 0, stream>>>(obuf, ein, topi, posmj, wmaj,
                                               out);
}